// Round 3
// baseline (42.990 us; speedup 1.0000x reference)
//
#include <hip/hip_runtime.h>

#define DDIM  128
#define SCH   16          // samples per slot
#define NSLOT 5           // slots per relation (handles up to 80 samples/relation; max ~35 here)
#define HALF  64          // output columns per block

__global__ __launch_bounds__(256) void transr_fused(
    const int* __restrict__ h, const int* __restrict__ r,
    const int* __restrict__ pos_t, const int* __restrict__ neg_t,
    const float* __restrict__ ent, const float* __restrict__ rel,
    const float* __restrict__ M, float* __restrict__ out,
    int B, int R)
{
    const int bid  = blockIdx.x;
    const int rb   = bid % R;          // R % 8 == 0 -> all blocks of a relation share an XCD
    const int rest = bid / R;
    const int slot = rest % NSLOT;
    const int half = rest / NSLOT;     // 0 or 1
    const int t  = threadIdx.x;
    const int wv = t >> 6;
    const int ln = t & 63;

    __shared__ int   list_s[SCH];
    __shared__ int   wsum_s[4];
    __shared__ int   cnt_s;
    __shared__ float Wl[DDIM][HALF];      // 32 KB, this block's W column-half
    __shared__ float Xl[3 * SCH][DDIM];   // 24 KB, gathered embedding rows

    // ---- deterministic self-bucketing: scan r[] with ballot compaction ----
    const int base = slot * SCH;
    int seen = 0;                      // matches found so far (block-uniform)
    for (int i0 = 0; i0 < B; i0 += 256) {
        const int  idx = i0 + t;
        const bool f   = (idx < B) && (r[idx] == rb);
        const unsigned long long m = __ballot(f);
        const int wc = __popcll(m);
        if (ln == 0) wsum_s[wv] = wc;
        __syncthreads();
        int wpre = 0;
        #pragma unroll
        for (int w = 0; w < 4; ++w) wpre += (w < wv) ? wsum_s[w] : 0;
        const int tot = wsum_s[0] + wsum_s[1] + wsum_s[2] + wsum_s[3];
        const int pos = seen + wpre + __popcll(m & ((1ull << ln) - 1ull));
        if (f && pos >= base && pos < base + SCH) list_s[pos - base] = idx;
        seen += tot;
        __syncthreads();
        if (seen >= base + SCH) break;     // block-uniform
    }
    if (t == 0) cnt_s = min(max(seen - base, 0), SCH);
    __syncthreads();
    const int cnt = cnt_s;
    if (cnt <= 0) return;

    // ---- stage W column-half into LDS (each element read once per block) ----
    const float* __restrict__ Wg = M + (size_t)rb * DDIM * DDIM + half * HALF;
    for (int lin = t; lin < DDIM * (HALF / 4); lin += 256) {   // 2048 float4
        const int d_ = lin >> 4;
        const int c4 = lin & 15;
        *(float4*)(&Wl[d_][c4 * 4]) = *(const float4*)(Wg + (size_t)d_ * DDIM + c4 * 4);
    }

    // ---- stage gathered X rows (h/pos/neg interleaved, 3 per sample) ----
    for (int lin = t; lin < 3 * cnt * (DDIM / 4); lin += 256) {
        const int row = lin >> 5;
        const int c4  = lin & 31;
        const int j   = row / 3;
        const int v   = row - 3 * j;
        const int sidx = list_s[j];
        const int eid  = (v == 0) ? h[sidx] : (v == 1) ? pos_t[sidx] : neg_t[sidx];
        *(float4*)(&Xl[row][c4 * 4]) = *(const float4*)(ent + (size_t)eid * DDIM + c4 * 4);
    }
    __syncthreads();

    // ---- compute: thread (tx,ty) -> sample ty, cols half*64 + tx*4 .. +3 ----
    const int tx = t & 15;
    const int ty = t >> 4;             // 0..15 == sample within slot
    float acc[3][4] = {};
    const float* xr = &Xl[ty * 3][0];

#define FMA4(xv, cmp, wv4)                              \
    acc[0][0] = fmaf(x0.cmp, wv4.x, acc[0][0]);         \
    acc[0][1] = fmaf(x0.cmp, wv4.y, acc[0][1]);         \
    acc[0][2] = fmaf(x0.cmp, wv4.z, acc[0][2]);         \
    acc[0][3] = fmaf(x0.cmp, wv4.w, acc[0][3]);         \
    acc[1][0] = fmaf(x1.cmp, wv4.x, acc[1][0]);         \
    acc[1][1] = fmaf(x1.cmp, wv4.y, acc[1][1]);         \
    acc[1][2] = fmaf(x1.cmp, wv4.z, acc[1][2]);         \
    acc[1][3] = fmaf(x1.cmp, wv4.w, acc[1][3]);         \
    acc[2][0] = fmaf(x2.cmp, wv4.x, acc[2][0]);         \
    acc[2][1] = fmaf(x2.cmp, wv4.y, acc[2][1]);         \
    acc[2][2] = fmaf(x2.cmp, wv4.z, acc[2][2]);         \
    acc[2][3] = fmaf(x2.cmp, wv4.w, acc[2][3]);

    #pragma unroll 4
    for (int d0 = 0; d0 < DDIM; d0 += 4) {
        const float4 x0 = *(const float4*)(xr + 0 * DDIM + d0);
        const float4 x1 = *(const float4*)(xr + 1 * DDIM + d0);
        const float4 x2 = *(const float4*)(xr + 2 * DDIM + d0);
        const float4 w0 = *(const float4*)(&Wl[d0 + 0][tx * 4]);
        const float4 w1 = *(const float4*)(&Wl[d0 + 1][tx * 4]);
        const float4 w2 = *(const float4*)(&Wl[d0 + 2][tx * 4]);
        const float4 w3 = *(const float4*)(&Wl[d0 + 3][tx * 4]);
        FMA4(x0, x, w0)
        FMA4(x1, y, w1)
        FMA4(x2, z, w2)
        FMA4(x3, w, w3)
    }
#undef FMA4

    if (ty < cnt) {
        const size_t s   = (size_t)list_s[ty];
        const size_t col = (size_t)half * HALF + tx * 4;
        *(float4*)(out + s * DDIM + col) =
            make_float4(acc[0][0], acc[0][1], acc[0][2], acc[0][3]);                   // trans_h
        *(float4*)(out + (size_t)2 * B * DDIM + s * DDIM + col) =
            make_float4(acc[1][0], acc[1][1], acc[1][2], acc[1][3]);                   // trans_pos
        *(float4*)(out + (size_t)3 * B * DDIM + s * DDIM + col) =
            make_float4(acc[2][0], acc[2][1], acc[2][2], acc[2][3]);                   // trans_neg
    }

    // ---- r_e gather for this column-half ----
    for (int lin = t; lin < cnt * (HALF / 4); lin += 256) {
        const int j  = lin >> 4;
        const int c4 = lin & 15;
        const float4 v = *(const float4*)(rel + (size_t)rb * DDIM + half * HALF + c4 * 4);
        *(float4*)(out + (size_t)B * DDIM + (size_t)list_s[j] * DDIM + half * HALF + c4 * 4) = v;
    }
}

extern "C" void kernel_launch(void* const* d_in, const int* in_sizes, int n_in,
                              void* d_out, int out_size, void* d_ws, size_t ws_size,
                              hipStream_t stream) {
    const int*   h     = (const int*)d_in[0];
    const int*   r     = (const int*)d_in[1];
    const int*   pos_t = (const int*)d_in[2];
    const int*   neg_t = (const int*)d_in[3];
    const float* ent   = (const float*)d_in[4];
    const float* rel   = (const float*)d_in[5];
    const float* M     = (const float*)d_in[6];
    float*       out   = (float*)d_out;

    const int B = in_sizes[0];
    const int R = in_sizes[5] / DDIM;

    const int grid = R * NSLOT * 2;
    transr_fused<<<dim3(grid), dim3(256), 0, stream>>>(
        h, r, pos_t, neg_t, ent, rel, M, out, B, R);
}

// Round 5
// 32.032 us; speedup vs baseline: 1.3421x; 1.3421x over previous
//
#include <hip/hip_runtime.h>

#define DDIM   128
#define HALF   64          // output columns per block
#define SCH    16          // samples per compute chunk
#define SEGCAP 96          // per-wave segment cap (actual data max ~15 per quarter)
#define XROWS  (3 * SCH)
#define XPAD   132         // X row stride in floats (528B, de-aliases banks)

__global__ __launch_bounds__(256) void transr_fused(
    const int* __restrict__ h, const int* __restrict__ r,
    const int* __restrict__ pos_t, const int* __restrict__ neg_t,
    const float* __restrict__ ent, const float* __restrict__ rel,
    const float* __restrict__ M, float* __restrict__ out,
    int B, int R)
{
    const int bid  = blockIdx.x;
    const int rb   = bid % R;
    const int half = bid / R;          // 0 or 1
    const int t  = threadIdx.x;
    const int wv = t >> 6;
    const int ln = t & 63;

    __shared__ float Wl[DDIM][HALF];        // 32 KB
    __shared__ float Xl[XROWS][XPAD];       // 25.3 KB
    __shared__ int   seg[4][SEGCAP];
    __shared__ int   wcnt[4];
    __shared__ int   list_s[4 * SEGCAP];

    // ---- stage W column-half into LDS (issue first: longest-latency loads) ----
    const float* __restrict__ Wg = M + (size_t)rb * DDIM * DDIM + half * HALF;
    #pragma unroll
    for (int lin = t; lin < DDIM * (HALF / 4); lin += 256) {   // 8 iters
        const int d_ = lin >> 4;
        const int c4 = lin & 15;
        *(float4*)(&Wl[d_][c4 * 4]) = *(const float4*)(Wg + (size_t)d_ * DDIM + c4 * 4);
    }

    // ---- per-wave ballot scan of one quarter of r[] (no barriers inside) ----
    int segn = 0;
    const int qlen  = B >> 2;
    const int qbase = wv * qlen;
    for (int i0 = 0; i0 < qlen; i0 += 64) {
        const int  idx = qbase + i0 + ln;
        const bool f   = (idx < B) && (r[idx] == rb);
        const unsigned long long m = __ballot(f);
        if (f) {
            const int p = segn + __popcll(m & ((1ull << ln) - 1ull));
            if (p < SEGCAP) seg[wv][p] = idx;
        }
        segn += __popcll(m);
    }
    if (ln == 0) wcnt[wv] = min(segn, SEGCAP);
    __syncthreads();

    const int c0 = wcnt[0], c1 = wcnt[1], c2 = wcnt[2], c3 = wcnt[3];
    const int cum1 = c0, cum2 = c0 + c1, cum3 = c0 + c1 + c2;
    const int cnt  = cum3 + c3;
    if (cnt == 0) return;

    // ---- compact segments into one ordered-enough list ----
    for (int lin = t; lin < cnt; lin += 256) {
        int w, k;
        if      (lin < cum1) { w = 0; k = lin;        }
        else if (lin < cum2) { w = 1; k = lin - cum1; }
        else if (lin < cum3) { w = 2; k = lin - cum2; }
        else                 { w = 3; k = lin - cum3; }
        list_s[lin] = seg[w][k];
    }
    __syncthreads();

    // ---- r_e gather for this column-half ----
    for (int lin = t; lin < cnt * (HALF / 4); lin += 256) {
        const int j  = lin >> 4;
        const int c4 = lin & 15;
        const float4 v = *(const float4*)(rel + (size_t)rb * DDIM + half * HALF + c4 * 4);
        *(float4*)(out + (size_t)B * DDIM + (size_t)list_s[j] * DDIM + half * HALF + c4 * 4) = v;
    }

    const int tx = t & 15;             // col group: 4 cols
    const int ty = t >> 4;             // sample within chunk

    // ---- chunk loop ----
    for (int ch = 0; ch < cnt; ch += SCH) {
        const int ccnt = min(SCH, cnt - ch);

        // stage X rows (3 per sample), float4-coalesced; pad with last valid sample
        for (int lin = t; lin < XROWS * (DDIM / 4); lin += 256) {   // 6 iters
            const int row = lin >> 5;
            const int c4  = lin & 31;
            int j = row / 3;
            const int v = row - 3 * j;
            if (j >= ccnt) j = ccnt - 1;
            const int sidx = list_s[ch + j];
            const int eid  = (v == 0) ? h[sidx] : (v == 1) ? pos_t[sidx] : neg_t[sidx];
            *(float4*)(&Xl[row][c4 * 4]) = *(const float4*)(ent + (size_t)eid * DDIM + c4 * 4);
        }
        __syncthreads();

        float acc[3][4] = {};

#define FMA12(cmp, wv4)                                  \
        acc[0][0] = fmaf(x0.cmp, wv4.x, acc[0][0]);      \
        acc[0][1] = fmaf(x0.cmp, wv4.y, acc[0][1]);      \
        acc[0][2] = fmaf(x0.cmp, wv4.z, acc[0][2]);      \
        acc[0][3] = fmaf(x0.cmp, wv4.w, acc[0][3]);      \
        acc[1][0] = fmaf(x1.cmp, wv4.x, acc[1][0]);      \
        acc[1][1] = fmaf(x1.cmp, wv4.y, acc[1][1]);      \
        acc[1][2] = fmaf(x1.cmp, wv4.z, acc[1][2]);      \
        acc[1][3] = fmaf(x1.cmp, wv4.w, acc[1][3]);      \
        acc[2][0] = fmaf(x2.cmp, wv4.x, acc[2][0]);      \
        acc[2][1] = fmaf(x2.cmp, wv4.y, acc[2][1]);      \
        acc[2][2] = fmaf(x2.cmp, wv4.z, acc[2][2]);      \
        acc[2][3] = fmaf(x2.cmp, wv4.w, acc[2][3]);

        #pragma unroll 4
        for (int d0 = 0; d0 < DDIM; d0 += 4) {
            const float4 x0 = *(const float4*)(&Xl[ty * 3 + 0][d0]);
            const float4 x1 = *(const float4*)(&Xl[ty * 3 + 1][d0]);
            const float4 x2 = *(const float4*)(&Xl[ty * 3 + 2][d0]);
            const float4 w0 = *(const float4*)(&Wl[d0 + 0][tx * 4]);
            const float4 w1 = *(const float4*)(&Wl[d0 + 1][tx * 4]);
            const float4 w2 = *(const float4*)(&Wl[d0 + 2][tx * 4]);
            const float4 w3 = *(const float4*)(&Wl[d0 + 3][tx * 4]);
            FMA12(x, w0)
            FMA12(y, w1)
            FMA12(z, w2)
            FMA12(w, w3)
        }
#undef FMA12

        if (ty < ccnt) {
            const size_t s   = (size_t)list_s[ch + ty];
            const size_t col = (size_t)half * HALF + tx * 4;
            *(float4*)(out + s * DDIM + col) =
                make_float4(acc[0][0], acc[0][1], acc[0][2], acc[0][3]);               // trans_h
            *(float4*)(out + (size_t)2 * B * DDIM + s * DDIM + col) =
                make_float4(acc[1][0], acc[1][1], acc[1][2], acc[1][3]);               // trans_pos
            *(float4*)(out + (size_t)3 * B * DDIM + s * DDIM + col) =
                make_float4(acc[2][0], acc[2][1], acc[2][2], acc[2][3]);               // trans_neg
        }
        __syncthreads();   // protect Xl before next chunk overwrites
    }
}

extern "C" void kernel_launch(void* const* d_in, const int* in_sizes, int n_in,
                              void* d_out, int out_size, void* d_ws, size_t ws_size,
                              hipStream_t stream) {
    const int*   h     = (const int*)d_in[0];
    const int*   r     = (const int*)d_in[1];
    const int*   pos_t = (const int*)d_in[2];
    const int*   neg_t = (const int*)d_in[3];
    const float* ent   = (const float*)d_in[4];
    const float* rel   = (const float*)d_in[5];
    const float* M     = (const float*)d_in[6];
    float*       out   = (float*)d_out;

    const int B = in_sizes[0];
    const int R = in_sizes[5] / DDIM;

    transr_fused<<<dim3(R * 2), dim3(256), 0, stream>>>(
        h, r, pos_t, neg_t, ent, rel, M, out, B, R);
}

// Round 6
// 19.512 us; speedup vs baseline: 2.2033x; 1.6417x over previous
//
#include <hip/hip_runtime.h>

#define DDIM   128
#define HALF   64          // output columns per block
#define SCH    21          // samples per compute chunk (63 rows + 1 pad)
#define MROWS  64
#define XSTRIDE 136        // bf16 row stride (272B = 17*16 -> conflict-free b128)
#define SEGCAP 96

typedef __attribute__((ext_vector_type(8))) short bf16x8;
typedef __attribute__((ext_vector_type(4))) float f32x4;

static __device__ inline unsigned short f2b(float f) {
    unsigned u = __float_as_uint(f);
    u += 0x7fff + ((u >> 16) & 1);      // round-to-nearest-even
    return (unsigned short)(u >> 16);
}

__global__ __launch_bounds__(256) void transr_mfma(
    const int* __restrict__ h, const int* __restrict__ r,
    const int* __restrict__ pos_t, const int* __restrict__ neg_t,
    const float* __restrict__ ent, const float* __restrict__ rel,
    const float* __restrict__ M, float* __restrict__ out,
    int B, int R)
{
    const int bid  = blockIdx.x;
    const int rb   = bid % R;
    const int half = bid / R;          // 0 or 1
    const int t  = threadIdx.x;
    const int wv = t >> 6;
    const int ln = t & 63;

    __shared__ __align__(16) unsigned short Xl[MROWS * XSTRIDE];   // 17.4 KB
    __shared__ __align__(16) unsigned short Wt[HALF  * XSTRIDE];   // 17.4 KB, W^T (n,k)
    __shared__ int seg[4][SEGCAP];
    __shared__ int wcnt[4];
    __shared__ int list_s[4 * SEGCAP];

    // ---- stage W^T half: fragment (nloc, g) needs W[8g..8g+7][half*64+nloc] ----
    {
        const float* __restrict__ Wg = M + (size_t)rb * DDIM * DDIM + half * HALF;
        const int g   = t >> 4;        // 0..15 (k-group)
        const int nl0 = t & 15;
        #pragma unroll
        for (int i = 0; i < 4; ++i) {
            const int nloc = nl0 + i * 16;
            bf16x8 v;
            #pragma unroll
            for (int jj = 0; jj < 8; ++jj)
                v[jj] = (short)f2b(Wg[(size_t)(g * 8 + jj) * DDIM + nloc]);
            *(bf16x8*)(&Wt[nloc * XSTRIDE + g * 8]) = v;
        }
    }

    // ---- per-wave ballot scan of one quarter of r[] ----
    int segn = 0;
    const int qlen  = B >> 2;
    const int qbase = wv * qlen;
    for (int i0 = 0; i0 < qlen; i0 += 64) {
        const int  idx = qbase + i0 + ln;
        const bool f   = (idx < B) && (r[idx] == rb);
        const unsigned long long m = __ballot(f);
        if (f) {
            const int p = segn + __popcll(m & ((1ull << ln) - 1ull));
            if (p < SEGCAP) seg[wv][p] = idx;
        }
        segn += __popcll(m);
    }
    if (ln == 0) wcnt[wv] = min(segn, SEGCAP);
    __syncthreads();

    const int c0 = wcnt[0], c1 = wcnt[1], c2 = wcnt[2], c3 = wcnt[3];
    const int cum1 = c0, cum2 = c0 + c1, cum3 = c0 + c1 + c2;
    const int cnt  = cum3 + c3;
    if (cnt == 0) return;

    for (int lin = t; lin < cnt; lin += 256) {
        int w, k;
        if      (lin < cum1) { w = 0; k = lin;        }
        else if (lin < cum2) { w = 1; k = lin - cum1; }
        else if (lin < cum3) { w = 2; k = lin - cum2; }
        else                 { w = 3; k = lin - cum3; }
        list_s[lin] = seg[w][k];
    }
    __syncthreads();

    // ---- r_e gather for this half ----
    for (int lin = t; lin < cnt * (HALF / 4); lin += 256) {
        const int j  = lin >> 4;
        const int c4 = lin & 15;
        const float4 v = *(const float4*)(rel + (size_t)rb * DDIM + half * HALF + c4 * 4);
        *(float4*)(out + (size_t)B * DDIM + (size_t)list_s[j] * DDIM + half * HALF + c4 * 4) = v;
    }

    // ---- chunk loop over samples ----
    for (int ch = 0; ch < cnt; ch += SCH) {
        const int ccnt = min(SCH, cnt - ch);
        const int rows_valid = 3 * ccnt;

        // stage X rows (bf16): row = 3*j + v; 1024 fragments, 4 per thread
        for (int lin = t; lin < MROWS * 16; lin += 256) {
            const int row = lin >> 4;
            const int g   = lin & 15;
            int j = row / 3;
            const int v = row - 3 * j;
            if (j >= ccnt) j = ccnt - 1;
            const int sidx = list_s[ch + j];
            const int eid  = (v == 0) ? h[sidx] : (v == 1) ? pos_t[sidx] : neg_t[sidx];
            const float4 a = *(const float4*)(ent + (size_t)eid * DDIM + g * 8);
            const float4 b = *(const float4*)(ent + (size_t)eid * DDIM + g * 8 + 4);
            bf16x8 x;
            x[0] = (short)f2b(a.x); x[1] = (short)f2b(a.y);
            x[2] = (short)f2b(a.z); x[3] = (short)f2b(a.w);
            x[4] = (short)f2b(b.x); x[5] = (short)f2b(b.y);
            x[6] = (short)f2b(b.z); x[7] = (short)f2b(b.w);
            *(bf16x8*)(&Xl[row * XSTRIDE + g * 8]) = x;
        }
        __syncthreads();

        // ---- MFMA: wave = M-tile, 4 N-tiles x 4 K-steps ----
        const int mt = wv;
        f32x4 acc0 = {0.f, 0.f, 0.f, 0.f};
        f32x4 acc1 = {0.f, 0.f, 0.f, 0.f};
        f32x4 acc2 = {0.f, 0.f, 0.f, 0.f};
        f32x4 acc3 = {0.f, 0.f, 0.f, 0.f};
        const int lr = ln & 15;
        const int lg = ln >> 4;
        #pragma unroll
        for (int ks = 0; ks < 4; ++ks) {
            const int g = ks * 4 + lg;
            const bf16x8 a = *(const bf16x8*)(&Xl[(mt * 16 + lr) * XSTRIDE + g * 8]);
            const bf16x8 b0 = *(const bf16x8*)(&Wt[(0 * 16 + lr) * XSTRIDE + g * 8]);
            const bf16x8 b1 = *(const bf16x8*)(&Wt[(1 * 16 + lr) * XSTRIDE + g * 8]);
            const bf16x8 b2 = *(const bf16x8*)(&Wt[(2 * 16 + lr) * XSTRIDE + g * 8]);
            const bf16x8 b3 = *(const bf16x8*)(&Wt[(3 * 16 + lr) * XSTRIDE + g * 8]);
            acc0 = __builtin_amdgcn_mfma_f32_16x16x32_bf16(a, b0, acc0, 0, 0, 0);
            acc1 = __builtin_amdgcn_mfma_f32_16x16x32_bf16(a, b1, acc1, 0, 0, 0);
            acc2 = __builtin_amdgcn_mfma_f32_16x16x32_bf16(a, b2, acc2, 0, 0, 0);
            acc3 = __builtin_amdgcn_mfma_f32_16x16x32_bf16(a, b3, acc3, 0, 0, 0);
        }

        // ---- epilogue: C layout col=lane&15, row=(lane>>4)*4+reg ----
        const size_t BD = (size_t)B * DDIM;
        #pragma unroll
        for (int q = 0; q < 4; ++q) {
            const int row = mt * 16 + lg * 4 + q;
            if (row < rows_valid) {
                const int jj = row / 3;
                const int v  = row - 3 * jj;
                const size_t s = (size_t)list_s[ch + jj];
                float* bp = (v == 0) ? out : (v == 1) ? (out + 2 * BD) : (out + 3 * BD);
                bp += s * DDIM + half * HALF + lr;
                bp[0]  = acc0[q];
                bp[16] = acc1[q];
                bp[32] = acc2[q];
                bp[48] = acc3[q];
            }
        }
        __syncthreads();   // protect Xl before next chunk restage
    }
}

extern "C" void kernel_launch(void* const* d_in, const int* in_sizes, int n_in,
                              void* d_out, int out_size, void* d_ws, size_t ws_size,
                              hipStream_t stream) {
    const int*   h     = (const int*)d_in[0];
    const int*   r     = (const int*)d_in[1];
    const int*   pos_t = (const int*)d_in[2];
    const int*   neg_t = (const int*)d_in[3];
    const float* ent   = (const float*)d_in[4];
    const float* rel   = (const float*)d_in[5];
    const float* M     = (const float*)d_in[6];
    float*       out   = (float*)d_out;

    const int B = in_sizes[0];
    const int R = in_sizes[5] / DDIM;

    transr_mfma<<<dim3(R * 2), dim3(256), 0, stream>>>(
        h, r, pos_t, neg_t, ent, rel, M, out, B, R);
}

// Round 7
// 17.226 us; speedup vs baseline: 2.4956x; 1.1327x over previous
//
#include <hip/hip_runtime.h>

#define DDIM   128
#define QCOL   32          // output columns per block (quarter)
#define SCH    21          // samples per compute chunk (63 rows + 1 pad)
#define MROWS  64
#define XSTRIDE 136        // bf16 row stride (272B -> conflict-free b128)
#define SEGCAP 96

typedef __attribute__((ext_vector_type(8))) short bf16x8;
typedef __attribute__((ext_vector_type(4))) float f32x4;

static __device__ inline unsigned short f2b(float f) {
    unsigned u = __float_as_uint(f);
    u += 0x7fff + ((u >> 16) & 1);      // round-to-nearest-even
    return (unsigned short)(u >> 16);
}

__global__ __launch_bounds__(256) void transr_mfma(
    const int* __restrict__ h, const int* __restrict__ r,
    const int* __restrict__ pos_t, const int* __restrict__ neg_t,
    const float* __restrict__ ent, const float* __restrict__ rel,
    const float* __restrict__ M, float* __restrict__ out,
    int B, int R)
{
    const int bid  = blockIdx.x;
    const int rb   = bid % R;          // R % 8 == 0: all 4 quarters of rb on one XCD
    const int qc   = bid / R;          // 0..3 column quarter
    const int t  = threadIdx.x;
    const int wv = t >> 6;
    const int ln = t & 63;

    __shared__ __align__(16) unsigned short Xl[MROWS * XSTRIDE];   // 17.4 KB
    __shared__ __align__(16) unsigned short Wt[QCOL  * XSTRIDE];   // 8.7 KB, W^T (n,k)
    __shared__ int seg[4][SEGCAP];
    __shared__ int wcnt[4];
    __shared__ int list_s[4 * SEGCAP];

    // ---- stage W^T quarter: fragment (nloc,g) = W[8g..8g+7][qc*32+nloc] ----
    {
        const float* __restrict__ Wg = M + (size_t)rb * DDIM * DDIM + qc * QCOL;
        const int g   = t >> 4;        // 0..15 (k-group)
        const int nl0 = t & 15;
        #pragma unroll
        for (int i = 0; i < 2; ++i) {
            const int nloc = nl0 + i * 16;
            bf16x8 v;
            #pragma unroll
            for (int jj = 0; jj < 8; ++jj)
                v[jj] = (short)f2b(Wg[(size_t)(g * 8 + jj) * DDIM + nloc]);
            *(bf16x8*)(&Wt[nloc * XSTRIDE + g * 8]) = v;
        }
    }

    // ---- per-wave ballot scan of one quarter of r[] ----
    int segn = 0;
    const int qlen  = B >> 2;
    const int qbase = wv * qlen;
    for (int i0 = 0; i0 < qlen; i0 += 64) {
        const int  idx = qbase + i0 + ln;
        const bool f   = (idx < B) && (r[idx] == rb);
        const unsigned long long m = __ballot(f);
        if (f) {
            const int p = segn + __popcll(m & ((1ull << ln) - 1ull));
            if (p < SEGCAP) seg[wv][p] = idx;
        }
        segn += __popcll(m);
    }
    if (ln == 0) wcnt[wv] = min(segn, SEGCAP);
    __syncthreads();

    const int c0 = wcnt[0], c1 = wcnt[1], c2 = wcnt[2], c3 = wcnt[3];
    const int cum1 = c0, cum2 = c0 + c1, cum3 = c0 + c1 + c2;
    const int cnt  = cum3 + c3;
    if (cnt == 0) return;

    for (int lin = t; lin < cnt; lin += 256) {
        int w, k;
        if      (lin < cum1) { w = 0; k = lin;        }
        else if (lin < cum2) { w = 1; k = lin - cum1; }
        else if (lin < cum3) { w = 2; k = lin - cum2; }
        else                 { w = 3; k = lin - cum3; }
        list_s[lin] = seg[w][k];
    }
    __syncthreads();

    // ---- r_e gather for this quarter ----
    for (int lin = t; lin < cnt * (QCOL / 4); lin += 256) {
        const int j  = lin >> 3;
        const int c4 = lin & 7;
        const float4 v = *(const float4*)(rel + (size_t)rb * DDIM + qc * QCOL + c4 * 4);
        *(float4*)(out + (size_t)B * DDIM + (size_t)list_s[j] * DDIM + qc * QCOL + c4 * 4) = v;
    }

    // ---- chunk loop over samples ----
    for (int ch = 0; ch < cnt; ch += SCH) {
        const int ccnt = min(SCH, cnt - ch);
        const int rows_valid = 3 * ccnt;

        // stage X rows (bf16): row = 3*j + v; 1024 fragments, 4 per thread
        for (int lin = t; lin < MROWS * 16; lin += 256) {
            const int row = lin >> 4;
            const int g   = lin & 15;
            int j = row / 3;
            const int v = row - 3 * j;
            if (j >= ccnt) j = ccnt - 1;
            const int sidx = list_s[ch + j];
            const int eid  = (v == 0) ? h[sidx] : (v == 1) ? pos_t[sidx] : neg_t[sidx];
            const float4 a = *(const float4*)(ent + (size_t)eid * DDIM + g * 8);
            const float4 b = *(const float4*)(ent + (size_t)eid * DDIM + g * 8 + 4);
            bf16x8 x;
            x[0] = (short)f2b(a.x); x[1] = (short)f2b(a.y);
            x[2] = (short)f2b(a.z); x[3] = (short)f2b(a.w);
            x[4] = (short)f2b(b.x); x[5] = (short)f2b(b.y);
            x[6] = (short)f2b(b.z); x[7] = (short)f2b(b.w);
            *(bf16x8*)(&Xl[row * XSTRIDE + g * 8]) = x;
        }
        __syncthreads();

        // ---- MFMA: wave = M-tile, 2 N-tiles x 4 K-steps ----
        const int mt = wv;
        f32x4 acc0 = {0.f, 0.f, 0.f, 0.f};
        f32x4 acc1 = {0.f, 0.f, 0.f, 0.f};
        const int lr = ln & 15;
        const int lg = ln >> 4;
        #pragma unroll
        for (int ks = 0; ks < 4; ++ks) {
            const int g = ks * 4 + lg;
            const bf16x8 a  = *(const bf16x8*)(&Xl[(mt * 16 + lr) * XSTRIDE + g * 8]);
            const bf16x8 b0 = *(const bf16x8*)(&Wt[(0 * 16 + lr) * XSTRIDE + g * 8]);
            const bf16x8 b1 = *(const bf16x8*)(&Wt[(1 * 16 + lr) * XSTRIDE + g * 8]);
            acc0 = __builtin_amdgcn_mfma_f32_16x16x32_bf16(a, b0, acc0, 0, 0, 0);
            acc1 = __builtin_amdgcn_mfma_f32_16x16x32_bf16(a, b1, acc1, 0, 0, 0);
        }

        // ---- epilogue: C layout col=lane&15, row=(lane>>4)*4+reg ----
        const size_t BD = (size_t)B * DDIM;
        #pragma unroll
        for (int q = 0; q < 4; ++q) {
            const int row = mt * 16 + lg * 4 + q;
            if (row < rows_valid) {
                const int jj = row / 3;
                const int v  = row - 3 * jj;
                const size_t s = (size_t)list_s[ch + jj];
                float* bp = (v == 0) ? out : (v == 1) ? (out + 2 * BD) : (out + 3 * BD);
                bp += s * DDIM + qc * QCOL + lr;
                bp[0]  = acc0[q];
                bp[16] = acc1[q];
            }
        }
        __syncthreads();   // protect Xl before next chunk restage
    }
}

extern "C" void kernel_launch(void* const* d_in, const int* in_sizes, int n_in,
                              void* d_out, int out_size, void* d_ws, size_t ws_size,
                              hipStream_t stream) {
    const int*   h     = (const int*)d_in[0];
    const int*   r     = (const int*)d_in[1];
    const int*   pos_t = (const int*)d_in[2];
    const int*   neg_t = (const int*)d_in[3];
    const float* ent   = (const float*)d_in[4];
    const float* rel   = (const float*)d_in[5];
    const float* M     = (const float*)d_in[6];
    float*       out   = (float*)d_out;

    const int B = in_sizes[0];
    const int R = in_sizes[5] / DDIM;

    transr_mfma<<<dim3(R * 4), dim3(256), 0, stream>>>(
        h, r, pos_t, neg_t, ent, rel, M, out, B, R);
}